// Round 1
// baseline (73.208 us; speedup 1.0000x reference)
//
#include <hip/hip_runtime.h>

#define MB   2048   // model batches
#define NP   8192   // num points (scan length)
#define NF   8      // number of functions
#define RM   51     // removed leading iterations
#define NCH  64     // chunks per batch
#define CH   128    // NP / NCH, steps per chunk
#define SEG  32     // staged t per LDS tile
#define NSEG 4      // CH / SEG

// ws layout: maps (AoS 8 floats per (c,b)) = NCH*MB*8 floats = 4 MB
//            pe   (float2 per (c,b))       = NCH*MB*2 floats = 1 MB

// ---------------- Phase 1: per-chunk affine composition ----------------
__global__ __launch_bounds__(256) void ifs_phase1(
    const int* __restrict__ idxg, const float* __restrict__ W,
    const float* __restrict__ B, float4* __restrict__ maps)
{
    __shared__ int tile[256][SEG + 1];             // +1 pad: 2-way (free) bank access
    __shared__ __align__(16) float tbl[NF][8];     // {w00,w01,w10,w11,b0,b1,0,0}
    const int tid = threadIdx.x;
    if (tid < NF) {
        tbl[tid][0] = W[tid*4+0]; tbl[tid][1] = W[tid*4+1];
        tbl[tid][2] = W[tid*4+2]; tbl[tid][3] = W[tid*4+3];
        tbl[tid][4] = B[tid*2+0]; tbl[tid][5] = B[tid*2+1];
        tbl[tid][6] = 0.f;        tbl[tid][7] = 0.f;
    }
    const int c  = blockIdx.x >> 3;        // chunk id
    const int b0 = (blockIdx.x & 7) << 8;  // first batch of this block
    const int x4 = tid & 7, yy = tid >> 3;

    float a00 = 1.f, a01 = 0.f, a10 = 0.f, a11 = 1.f, c0 = 0.f, c1 = 0.f;

    for (int seg = 0; seg < NSEG; ++seg) {
        const int tb = c * CH + seg * SEG;
        // cooperative coalesced load: 256 rows x 32 t, int4 per thread per pass
        #pragma unroll
        for (int p = 0; p < 8; ++p) {
            const int row = yy + p * 32;
            const int4 v = *(const int4*)(idxg + (size_t)(b0 + row) * NP + tb + x4 * 4);
            tile[row][x4*4+0] = v.x; tile[row][x4*4+1] = v.y;
            tile[row][x4*4+2] = v.z; tile[row][x4*4+3] = v.w;
        }
        __syncthreads();
        #pragma unroll
        for (int s = 0; s < SEG; ++s) {
            const int f = tile[tid][s];
            const float4 wl = *(const float4*)&tbl[f][0];
            const float4 wh = *(const float4*)&tbl[f][4];
            const float na00 = wl.x*a00 + wl.y*a10;
            const float na01 = wl.x*a01 + wl.y*a11;
            const float na10 = wl.z*a00 + wl.w*a10;
            const float na11 = wl.z*a01 + wl.w*a11;
            const float nc0  = wl.x*c0  + wl.y*c1 + wh.x;
            const float nc1  = wl.z*c0  + wl.w*c1 + wh.y;
            a00 = na00; a01 = na01; a10 = na10; a11 = na11; c0 = nc0; c1 = nc1;
        }
        __syncthreads();
    }
    const size_t n = ((size_t)c * MB + b0 + tid) * 2;
    maps[n]     = make_float4(a00, a01, a10, a11);
    maps[n + 1] = make_float4(c0,  c1,  0.f, 0.f);
}

// ---------------- Phase 2: sequential scan over chunk maps ----------------
__global__ __launch_bounds__(64) void ifs_phase2(
    const float2* __restrict__ point, const float4* __restrict__ maps,
    float2* __restrict__ pe)
{
    const int b = blockIdx.x * 64 + threadIdx.x;
    float2 p = point[b];
    float4 lo = maps[(size_t)b * 2];
    float4 hi = maps[(size_t)b * 2 + 1];
    for (int c = 0; c < NCH; ++c) {
        float4 nlo = lo, nhi = hi;
        if (c + 1 < NCH) {  // prefetch next chunk's map
            nlo = maps[((size_t)(c + 1) * MB + b) * 2];
            nhi = maps[((size_t)(c + 1) * MB + b) * 2 + 1];
        }
        pe[(size_t)c * MB + b] = p;   // entry state of chunk c
        const float np0 = lo.x * p.x + lo.y * p.y + hi.x;
        const float np1 = lo.z * p.x + lo.w * p.y + hi.y;
        p.x = np0; p.y = np1;
        lo = nlo; hi = nhi;
    }
}

// ---------------- Phase 3: replay chunks, write outputs ----------------
__global__ __launch_bounds__(256) void ifs_phase3(
    const int* __restrict__ idxg, const float* __restrict__ W,
    const float* __restrict__ B, const float* __restrict__ OPS,
    const float2* __restrict__ pe, float* __restrict__ out)
{
    __shared__ int tile[256][SEG + 1];
    __shared__ __align__(16) float tbl[NF][8];     // {w00,w01,w10,w11,b0,b1,op,0}
    const int tid = threadIdx.x;
    if (tid < NF) {
        tbl[tid][0] = W[tid*4+0]; tbl[tid][1] = W[tid*4+1];
        tbl[tid][2] = W[tid*4+2]; tbl[tid][3] = W[tid*4+3];
        tbl[tid][4] = B[tid*2+0]; tbl[tid][5] = B[tid*2+1];
        tbl[tid][6] = OPS[tid];   tbl[tid][7] = 0.f;
    }
    const int c  = blockIdx.x >> 3;
    const int b0 = (blockIdx.x & 7) << 8;
    const int b  = b0 + tid;
    const int x4 = tid & 7, yy = tid >> 3;

    float2 p = pe[(size_t)c * MB + b];

    for (int seg = 0; seg < NSEG; ++seg) {
        const int tb = c * CH + seg * SEG;
        #pragma unroll
        for (int p8 = 0; p8 < 8; ++p8) {
            const int row = yy + p8 * 32;
            const int4 v = *(const int4*)(idxg + (size_t)(b0 + row) * NP + tb + x4 * 4);
            tile[row][x4*4+0] = v.x; tile[row][x4*4+1] = v.y;
            tile[row][x4*4+2] = v.z; tile[row][x4*4+3] = v.w;
        }
        __syncthreads();
        #pragma unroll
        for (int s = 0; s < SEG; ++s) {
            const int f = tile[tid][s];
            const float4 wl = *(const float4*)&tbl[f][0];
            const float4 wh = *(const float4*)&tbl[f][4];
            const float np0 = wl.x * p.x + wl.y * p.y + wh.x;
            const float np1 = wl.z * p.x + wl.w * p.y + wh.y;
            p.x = np0; p.y = np1;
            const int t = c * CH + seg * SEG + s;
            if (t >= RM) {
                float* o = out + ((size_t)(t - RM) * MB + b) * 3;
                o[0] = p.x; o[1] = p.y; o[2] = wh.z;
            }
        }
        __syncthreads();
    }
}

extern "C" void kernel_launch(void* const* d_in, const int* in_sizes, int n_in,
                              void* d_out, int out_size, void* d_ws, size_t ws_size,
                              hipStream_t stream) {
    const float* point = (const float*)d_in[0];  // [2048,2,1]
    const float* W     = (const float*)d_in[1];  // [8,2,2]
    const float* B     = (const float*)d_in[2];  // [8,2,1]
    const float* OPS   = (const float*)d_in[3];  // [8]
    const int*   idx   = (const int*)  d_in[4];  // [2048,8192]
    float*       out   = (float*)d_out;          // [(8192-51)*2048, 3]

    float*  ws   = (float*)d_ws;
    float4* maps = (float4*)ws;                              // 4 MB
    float2* pe   = (float2*)(ws + (size_t)NCH * MB * 8);     // 1 MB

    ifs_phase1<<<NCH * (MB / 256), 256, 0, stream>>>(idx, W, B, maps);
    ifs_phase2<<<MB / 64, 64, 0, stream>>>((const float2*)point, maps, pe);
    ifs_phase3<<<NCH * (MB / 256), 256, 0, stream>>>(idx, W, B, OPS, pe, out);
}